// Round 2
// baseline (463.755 us; speedup 1.0000x reference)
//
#include <hip/hip_runtime.h>
#include <hip/hip_cooperative_groups.h>
#include <math.h>

namespace cg = cooperative_groups;

#define D 2048
#define NROWS 8192      // B*T = 4*2048
#define NBUF 512
#define GB 1024         // cooperative grid blocks (4/CU, 16 waves/CU)
#define RCHUNKS 512     // row chunks in phase A
#define RPC 16          // rows per chunk (RCHUNKS*RPC = NROWS)
#define ROWS_PER_BLK 8  // phase E rows per block (GB*ROWS_PER_BLK = NROWS)

// tanh-GELU via sigmoid identity: 0.5*x*(1+tanh(a*(x+0.044715 x^3))) = x*sigmoid(2*a*u)
__device__ __forceinline__ float gelu_f(float v) {
    float u = v * (1.0f + 0.044715f * v * v);
    float t = -2.0f * 0.7978845608028654f * u;
    return v / (1.0f + __expf(t));
}

// One cooperative kernel: A) gelu col-partials  B) reduce->ysum  C) sims dots
// D) argmax+scalars (block 0)  E) per-row tok_sim + gelu(x + c*(s-g)).
// partial scratch [RCHUNKS][D] = 4 MB lives in `out` (consumed in B, overwritten in E).
__global__ __launch_bounds__(256, 4) void fused_all(
        const float* __restrict__ x, const float* __restrict__ buf,
        const float* __restrict__ xbuf, const float* __restrict__ inj,
        const float* __restrict__ xglobal, const int* __restrict__ mask,
        const float* __restrict__ log_inject, float* __restrict__ ws,
        float* __restrict__ out) {
    cg::grid_group grid = cg::this_grid();
    const int tid = threadIdx.x;
    const int b = blockIdx.x;
    const int lane = tid & 63, w = tid >> 6;

    float* ysum = ws;            // [2048]
    float* dotv = ws + 2048;     // [512]
    float* bn2  = ws + 2560;     // [512]
    float* yn2  = ws + 3072;     // [1]
    float* scal = ws + 3076;     // [4]
    float* partial = out;        // [RCHUNKS][D] scratch

    __shared__ float sa[4], sb[4];
    __shared__ float red[256];
    __shared__ float sv[256];
    __shared__ int   si[256];
    __shared__ int   s_idx;
    __shared__ float s_lvl;
    __shared__ float s_coef;

    // ---------- phase A: partial column sums of gelu(x) ----------
    {
        const int cg4 = (b & 1) * 256 + tid;     // float4 col group [0,512)
        const int r0 = (b >> 1) * RPC;
        const float4* x4 = (const float4*)x;
        float ax = 0.f, ay = 0.f, az = 0.f, aw = 0.f;
        #pragma unroll 8
        for (int r = 0; r < RPC; ++r) {
            float4 v = x4[(size_t)(r0 + r) * (D / 4) + cg4];
            ax += gelu_f(v.x); ay += gelu_f(v.y); az += gelu_f(v.z); aw += gelu_f(v.w);
        }
        float4 o; o.x = ax; o.y = ay; o.z = az; o.w = aw;
        ((float4*)partial)[(size_t)(b >> 1) * (D / 4) + cg4] = o;
    }
    grid.sync();

    // ---------- phase B: reduce RCHUNKS partials -> ysum[D] (64 blocks) ----------
    if (b < 64) {
        const int col   = b * 32 + (tid & 31);
        const int slice = tid >> 5;              // 8 slices of RCHUNKS/8
        float s = 0.f;
        #pragma unroll 8
        for (int k = 0; k < RCHUNKS / 8; ++k)
            s += partial[(size_t)(slice * (RCHUNKS / 8) + k) * D + col];
        red[tid] = s;
        __syncthreads();
        if (tid < 32) {
            float t = red[tid];
            #pragma unroll
            for (int j = 1; j < 8; ++j) t += red[j * 32 + tid];
            ysum[b * 32 + tid] = t;
        }
    }
    grid.sync();

    // ---------- phase C: per-buf-row dot+norm2; block NBUF does ||ysum||^2 ----------
    if (b <= NBUF) {
        float dacc = 0.f, nacc = 0.f;
        const float4* y4 = (const float4*)ysum;
        if (b < NBUF) {
            const float4* b4 = (const float4*)(buf + (size_t)b * D);
            #pragma unroll
            for (int c = tid; c < D / 4; c += 256) {
                float4 bv = b4[c]; float4 yv = y4[c];
                dacc += bv.x * yv.x + bv.y * yv.y + bv.z * yv.z + bv.w * yv.w;
                nacc += bv.x * bv.x + bv.y * bv.y + bv.z * bv.z + bv.w * bv.w;
            }
        } else {
            #pragma unroll
            for (int c = tid; c < D / 4; c += 256) {
                float4 yv = y4[c];
                dacc += yv.x * yv.x + yv.y * yv.y + yv.z * yv.z + yv.w * yv.w;
            }
        }
        #pragma unroll
        for (int off = 32; off; off >>= 1) {
            dacc += __shfl_down(dacc, off, 64);
            nacc += __shfl_down(nacc, off, 64);
        }
        if (lane == 0) { sa[w] = dacc; sb[w] = nacc; }
        __syncthreads();
        if (tid == 0) {
            float dt = sa[0] + sa[1] + sa[2] + sa[3];
            float nt = sb[0] + sb[1] + sb[2] + sb[3];
            if (b < NBUF) { dotv[b] = dt; bn2[b] = nt; }
            else yn2[0] = dt;
        }
    }
    grid.sync();

    // ---------- phase D: selection on block 0 ----------
    if (b == 0) {
        const float nm = fmaxf(sqrtf(yn2[0]) * (1.0f / 8192.0f), 1e-12f);
        float bestv = -INFINITY; int besti = 1 << 30;
        for (int i = tid; i < NBUF; i += 256) {
            float nb = fmaxf(sqrtf(bn2[i]), 1e-12f);
            float sim = (dotv[i] * (1.0f / 8192.0f)) / (nm * nb);
            if (!mask[i]) sim = -1.0f;
            if (sim > bestv || (sim == bestv && i < besti)) { bestv = sim; besti = i; }
        }
        sv[tid] = bestv; si[tid] = besti;
        __syncthreads();
        for (int s = 128; s; s >>= 1) {
            if (tid < s) {
                float v2 = sv[tid + s]; int i2 = si[tid + s];
                if (v2 > sv[tid] || (v2 == sv[tid] && i2 < si[tid])) { sv[tid] = v2; si[tid] = i2; }
            }
            __syncthreads();
        }
        if (tid == 0) {
            int idx = si[0];
            float max_sim = sv[0];
            float ib = fminf(fmaxf(__expf(log_inject[0]), 0.001f), 2.0f);
            float inear = inj[idx];
            float lvl = (max_sim > 0.85f) ? ((inear < 1e-6f) ? ib : inear * 2.0f) : inear;
            s_idx = idx; s_lvl = lvl;
        }
        __syncthreads();
        const int idx = s_idx;
        float n2 = 0.f, s2 = 0.f;
        const float* srp = xbuf + (size_t)idx * D;
        for (int d = tid; d < D; d += 256) {
            float sx = srp[d];
            float nd = sx - xglobal[d];
            n2 += nd * nd; s2 += sx * sx;
        }
        #pragma unroll
        for (int off = 32; off; off >>= 1) {
            n2 += __shfl_down(n2, off, 64);
            s2 += __shfl_down(s2, off, 64);
        }
        if (lane == 0) { sa[w] = n2; sb[w] = s2; }
        __syncthreads();
        if (tid == 0) {
            float nt = sa[0] + sa[1] + sa[2] + sa[3];
            float st = sb[0] + sb[1] + sb[2] + sb[3];
            scal[0] = s_lvl;                                  // inj_level
            scal[1] = 1.0f / fmaxf(sqrtf(nt), 1e-6f);         // 1/||nudge_dir||
            scal[2] = 1.0f / fmaxf(sqrtf(st), 1e-12f);        // 1/||stored_x||
            ((int*)scal)[3] = idx;                            // nearest_idx
        }
    }
    grid.sync();

    // ---------- phase E: per-row tok_sim + gelu(x + c*(s-g)) ----------
    const float inj_level = scal[0];
    const float rnudge    = scal[1];
    const float rstored   = scal[2];
    const int   idx       = ((const int*)scal)[3];

    const float4* srr = (const float4*)(xbuf + (size_t)idx * D);
    const float4* grr = (const float4*)xglobal;
    const float4 s0 = srr[tid], s1 = srr[tid + 256];   // loaded once, reused 8 rows
    const float4 g0 = grr[tid], g1 = grr[tid + 256];

    for (int r = 0; r < ROWS_PER_BLK; ++r) {
        const size_t row = (size_t)b * ROWS_PER_BLK + r;
        const float4* xr = (const float4*)(x + row * D);
        const float4 x0 = xr[tid], x1 = xr[tid + 256];

        float dxs = x0.x * s0.x + x0.y * s0.y + x0.z * s0.z + x0.w * s0.w
                  + x1.x * s1.x + x1.y * s1.y + x1.z * s1.z + x1.w * s1.w;
        float dxx = x0.x * x0.x + x0.y * x0.y + x0.z * x0.z + x0.w * x0.w
                  + x1.x * x1.x + x1.y * x1.y + x1.z * x1.z + x1.w * x1.w;

        #pragma unroll
        for (int off = 32; off; off >>= 1) {
            dxs += __shfl_down(dxs, off, 64);
            dxx += __shfl_down(dxx, off, 64);
        }
        if (lane == 0) { sa[w] = dxs; sb[w] = dxx; }
        __syncthreads();
        if (tid == 0) {
            float dt = sa[0] + sa[1] + sa[2] + sa[3];
            float nt = sb[0] + sb[1] + sb[2] + sb[3];
            float rx = 1.0f / fmaxf(sqrtf(nt), 1e-12f);
            float ts = fminf(fmaxf(dt * rx * rstored, 0.0f), 1.0f);  // tok_sim
            s_coef = (inj_level < 1e-6f) ? 0.0f : inj_level * ts * rnudge;
        }
        __syncthreads();
        const float c = s_coef;

        float4 o0, o1;
        o0.x = gelu_f(x0.x + c * (s0.x - g0.x));
        o0.y = gelu_f(x0.y + c * (s0.y - g0.y));
        o0.z = gelu_f(x0.z + c * (s0.z - g0.z));
        o0.w = gelu_f(x0.w + c * (s0.w - g0.w));
        o1.x = gelu_f(x1.x + c * (s1.x - g1.x));
        o1.y = gelu_f(x1.y + c * (s1.y - g1.y));
        o1.z = gelu_f(x1.z + c * (s1.z - g1.z));
        o1.w = gelu_f(x1.w + c * (s1.w - g1.w));

        float4* orow = (float4*)(out + row * D);
        orow[tid] = o0; orow[tid + 256] = o1;
        __syncthreads();   // protect sa/sb reuse next row
    }
}

extern "C" void kernel_launch(void* const* d_in, const int* in_sizes, int n_in,
                              void* d_out, int out_size, void* d_ws, size_t ws_size,
                              hipStream_t stream) {
    const float* x          = (const float*)d_in[0];
    const float* log_inject = (const float*)d_in[1];
    const float* buf        = (const float*)d_in[2];
    const float* xbuf       = (const float*)d_in[3];
    const float* inj        = (const float*)d_in[4];
    const float* xglobal    = (const float*)d_in[5];
    const int*   mask       = (const int*)d_in[6];
    float* out = (float*)d_out;
    float* ws  = (float*)d_ws;

    void* args[] = {(void*)&x, (void*)&buf, (void*)&xbuf, (void*)&inj,
                    (void*)&xglobal, (void*)&mask, (void*)&log_inject,
                    (void*)&ws, (void*)&out};
    hipLaunchCooperativeKernel((const void*)fused_all, dim3(GB), dim3(256),
                               args, 0, stream);
}

// Round 3
// 62.120 us; speedup vs baseline: 7.4655x; 7.4655x over previous
//
#include <hip/hip_runtime.h>
#include <math.h>

#define D 2048
#define NROWS 8192      // B*T = 4*2048
#define NBUF 512
#define RC 256          // row chunks in k1 (partial = RC*D*4 = 2 MB in ws)
#define ROWS_PER_CHUNK 32
#define K4_ROWS 2       // rows per k4 block

// tanh-GELU via sigmoid identity: 0.5*x*(1+tanh(a*(x+0.044715 x^3))) = x*sigmoid(2*a*u)
__device__ __forceinline__ float gelu_f(float v) {
    float u = v * (1.0f + 0.044715f * v * v);
    float t = -2.0f * 0.7978845608028654f * u;
    return v / (1.0f + __expf(t));
}

// ---- k1: partial column sums of gelu(x). grid (2, RC), block 256. 512 blocks = 2/CU.
__global__ __launch_bounds__(256) void k1_colsum(const float* __restrict__ x,
                                                 float* __restrict__ partial) {
    const int cg = blockIdx.x * 256 + threadIdx.x;   // float4 column group [0,512)
    const int r0 = blockIdx.y * ROWS_PER_CHUNK;
    const float4* x4 = (const float4*)x;
    float ax = 0.f, ay = 0.f, az = 0.f, aw = 0.f;
    #pragma unroll 4
    for (int r = 0; r < ROWS_PER_CHUNK; ++r) {
        float4 v = x4[(size_t)(r0 + r) * (D / 4) + cg];
        ax += gelu_f(v.x); ay += gelu_f(v.y); az += gelu_f(v.z); aw += gelu_f(v.w);
    }
    float4 o; o.x = ax; o.y = ay; o.z = az; o.w = aw;
    ((float4*)partial)[(size_t)blockIdx.y * (D / 4) + cg] = o;
}

// ---- k1b: reduce RC partials -> ysum[D]; also arms k2's completion counter. grid 64.
__global__ __launch_bounds__(256) void k1b_reduce(const float* __restrict__ partial,
                                                  float* __restrict__ ysum,
                                                  unsigned int* __restrict__ counter) {
    const int tid = threadIdx.x;
    if (blockIdx.x == 0 && tid == 0) *counter = 0u;
    const int col   = blockIdx.x * 32 + (tid & 31);
    const int slice = tid >> 5;                        // 8 slices of RC/8 k-values
    const int k0 = slice * (RC / 8);
    float s = 0.f;
    #pragma unroll 8
    for (int k = 0; k < RC / 8; ++k) s += partial[(size_t)(k0 + k) * D + col];
    __shared__ float red[256];
    red[tid] = s;
    __syncthreads();
    if (tid < 32) {
        float t = red[tid];
        #pragma unroll
        for (int j = 1; j < 8; ++j) t += red[j * 32 + tid];
        ysum[blockIdx.x * 32 + tid] = t;
    }
}

// ---- k2: per-buf-row dot+norm2 (block NBUF does ||ysum||^2); the LAST block to
//      finish runs the selection (old k3). grid NBUF+1.
__global__ __launch_bounds__(256) void k2_sims_select(
        const float* __restrict__ buf, const float* __restrict__ ysum,
        float* __restrict__ dotv, float* __restrict__ bn2, float* __restrict__ yn2,
        const int* __restrict__ mask, const float* __restrict__ inj,
        const float* __restrict__ log_inject, const float* __restrict__ xbuf,
        const float* __restrict__ xglobal, float* __restrict__ scal,
        unsigned int* __restrict__ counter) {
    const int tid = threadIdx.x;
    const int b = blockIdx.x;
    float dacc = 0.f, nacc = 0.f;
    const float4* y4 = (const float4*)ysum;
    if (b < NBUF) {
        const float4* b4 = (const float4*)(buf + (size_t)b * D);
        #pragma unroll
        for (int c = tid; c < D / 4; c += 256) {
            float4 bv = b4[c]; float4 yv = y4[c];
            dacc += bv.x * yv.x + bv.y * yv.y + bv.z * yv.z + bv.w * yv.w;
            nacc += bv.x * bv.x + bv.y * bv.y + bv.z * bv.z + bv.w * bv.w;
        }
    } else {
        #pragma unroll
        for (int c = tid; c < D / 4; c += 256) {
            float4 yv = y4[c];
            dacc += yv.x * yv.x + yv.y * yv.y + yv.z * yv.z + yv.w * yv.w;
        }
    }
    #pragma unroll
    for (int off = 32; off; off >>= 1) {
        dacc += __shfl_down(dacc, off, 64);
        nacc += __shfl_down(nacc, off, 64);
    }
    __shared__ float sa[4], sb[4];
    const int lane = tid & 63, w = tid >> 6;
    if (lane == 0) { sa[w] = dacc; sb[w] = nacc; }
    __syncthreads();
    if (tid == 0) {
        float dt = sa[0] + sa[1] + sa[2] + sa[3];
        float nt = sb[0] + sb[1] + sb[2] + sb[3];
        if (b < NBUF) { dotv[b] = dt; bn2[b] = nt; }
        else yn2[0] = dt;
    }

    // completion check: last block through runs the selection
    __shared__ int s_done;
    if (tid == 0) {
        __threadfence();
        unsigned int o = atomicAdd(counter, 1u);
        s_done = (o == (unsigned)NBUF);
    }
    __syncthreads();
    if (!s_done) return;
    __threadfence();

    __shared__ float sv[256];
    __shared__ int   si[256];
    const float nm = fmaxf(sqrtf(yn2[0]) * (1.0f / 8192.0f), 1e-12f);
    float bestv = -INFINITY; int besti = 1 << 30;
    for (int i = tid; i < NBUF; i += 256) {
        float nb = fmaxf(sqrtf(bn2[i]), 1e-12f);
        float sim = (dotv[i] * (1.0f / 8192.0f)) / (nm * nb);
        if (!mask[i]) sim = -1.0f;
        if (sim > bestv || (sim == bestv && i < besti)) { bestv = sim; besti = i; }
    }
    sv[tid] = bestv; si[tid] = besti;
    __syncthreads();
    for (int s = 128; s; s >>= 1) {
        if (tid < s) {
            float v2 = sv[tid + s]; int i2 = si[tid + s];
            if (v2 > sv[tid] || (v2 == sv[tid] && i2 < si[tid])) { sv[tid] = v2; si[tid] = i2; }
        }
        __syncthreads();
    }
    __shared__ int s_idx;
    __shared__ float s_lvl;
    if (tid == 0) {
        int idx = si[0];
        float max_sim = sv[0];
        float ib = fminf(fmaxf(__expf(log_inject[0]), 0.001f), 2.0f);
        float inear = inj[idx];
        float lvl = (max_sim > 0.85f) ? ((inear < 1e-6f) ? ib : inear * 2.0f) : inear;
        s_idx = idx; s_lvl = lvl;
    }
    __syncthreads();
    const int idx = s_idx;
    float n2 = 0.f, s2 = 0.f;
    const float* sr = xbuf + (size_t)idx * D;
    for (int d = tid; d < D; d += 256) {
        float sx = sr[d];
        float nd = sx - xglobal[d];
        n2 += nd * nd; s2 += sx * sx;
    }
    #pragma unroll
    for (int off = 32; off; off >>= 1) {
        n2 += __shfl_down(n2, off, 64);
        s2 += __shfl_down(s2, off, 64);
    }
    __shared__ float ra[4], rb[4];
    if (lane == 0) { ra[w] = n2; rb[w] = s2; }
    __syncthreads();
    if (tid == 0) {
        float nt = ra[0] + ra[1] + ra[2] + ra[3];
        float st = rb[0] + rb[1] + rb[2] + rb[3];
        scal[0] = s_lvl;                                  // inj_level
        scal[1] = 1.0f / fmaxf(sqrtf(nt), 1e-6f);         // 1/||nudge_dir||
        scal[2] = 1.0f / fmaxf(sqrtf(st), 1e-12f);        // 1/||stored_x||
        ((int*)scal)[3] = idx;                            // nearest_idx
    }
}

// ---- k4: two rows per block: tok_sims + gelu(x + c*(s-g)). grid NROWS/2, block 256.
__global__ __launch_bounds__(256) void k4_out(const float* __restrict__ x,
                                              const float* __restrict__ xbuf,
                                              const float* __restrict__ xglobal,
                                              const float* __restrict__ scal,
                                              float* __restrict__ out) {
    const int tid = threadIdx.x;
    const size_t row0 = (size_t)blockIdx.x * K4_ROWS;
    const float inj_level = scal[0];
    const float rnudge = scal[1];
    const float rstored = scal[2];
    const int idx = ((const int*)scal)[3];

    const float4* sr = (const float4*)(xbuf + (size_t)idx * D);
    const float4* gr = (const float4*)xglobal;
    const float4 s0 = sr[tid], s1 = sr[tid + 256];     // loaded once, reused 2 rows
    const float4 g0 = gr[tid], g1 = gr[tid + 256];

    const float4* xra = (const float4*)(x + row0 * D);
    const float4* xrb = (const float4*)(x + (row0 + 1) * D);
    const float4 a0 = xra[tid], a1 = xra[tid + 256];
    const float4 b0 = xrb[tid], b1 = xrb[tid + 256];

    float das = a0.x * s0.x + a0.y * s0.y + a0.z * s0.z + a0.w * s0.w
              + a1.x * s1.x + a1.y * s1.y + a1.z * s1.z + a1.w * s1.w;
    float dax = a0.x * a0.x + a0.y * a0.y + a0.z * a0.z + a0.w * a0.w
              + a1.x * a1.x + a1.y * a1.y + a1.z * a1.z + a1.w * a1.w;
    float dbs = b0.x * s0.x + b0.y * s0.y + b0.z * s0.z + b0.w * s0.w
              + b1.x * s1.x + b1.y * s1.y + b1.z * s1.z + b1.w * s1.w;
    float dbx = b0.x * b0.x + b0.y * b0.y + b0.z * b0.z + b0.w * b0.w
              + b1.x * b1.x + b1.y * b1.y + b1.z * b1.z + b1.w * b1.w;

    #pragma unroll
    for (int off = 32; off; off >>= 1) {
        das += __shfl_down(das, off, 64);
        dax += __shfl_down(dax, off, 64);
        dbs += __shfl_down(dbs, off, 64);
        dbx += __shfl_down(dbx, off, 64);
    }
    __shared__ float sas[4], sax[4], sbs[4], sbx[4];
    const int lane = tid & 63, w = tid >> 6;
    if (lane == 0) { sas[w] = das; sax[w] = dax; sbs[w] = dbs; sbx[w] = dbx; }
    __syncthreads();
    __shared__ float s_ca, s_cb;
    if (tid == 0) {
        float dta = sas[0] + sas[1] + sas[2] + sas[3];
        float nta = sax[0] + sax[1] + sax[2] + sax[3];
        float rxa = 1.0f / fmaxf(sqrtf(nta), 1e-12f);
        float tsa = fminf(fmaxf(dta * rxa * rstored, 0.0f), 1.0f);
        s_ca = (inj_level < 1e-6f) ? 0.0f : inj_level * tsa * rnudge;
        float dtb = sbs[0] + sbs[1] + sbs[2] + sbs[3];
        float ntb = sbx[0] + sbx[1] + sbx[2] + sbx[3];
        float rxb = 1.0f / fmaxf(sqrtf(ntb), 1e-12f);
        float tsb = fminf(fmaxf(dtb * rxb * rstored, 0.0f), 1.0f);
        s_cb = (inj_level < 1e-6f) ? 0.0f : inj_level * tsb * rnudge;
    }
    __syncthreads();
    const float ca = s_ca, cb = s_cb;

    float4 o0, o1;
    o0.x = gelu_f(a0.x + ca * (s0.x - g0.x));
    o0.y = gelu_f(a0.y + ca * (s0.y - g0.y));
    o0.z = gelu_f(a0.z + ca * (s0.z - g0.z));
    o0.w = gelu_f(a0.w + ca * (s0.w - g0.w));
    o1.x = gelu_f(a1.x + ca * (s1.x - g1.x));
    o1.y = gelu_f(a1.y + ca * (s1.y - g1.y));
    o1.z = gelu_f(a1.z + ca * (s1.z - g1.z));
    o1.w = gelu_f(a1.w + ca * (s1.w - g1.w));
    float4* orowa = (float4*)(out + row0 * D);
    orowa[tid] = o0; orowa[tid + 256] = o1;

    o0.x = gelu_f(b0.x + cb * (s0.x - g0.x));
    o0.y = gelu_f(b0.y + cb * (s0.y - g0.y));
    o0.z = gelu_f(b0.z + cb * (s0.z - g0.z));
    o0.w = gelu_f(b0.w + cb * (s0.w - g0.w));
    o1.x = gelu_f(b1.x + cb * (s1.x - g1.x));
    o1.y = gelu_f(b1.y + cb * (s1.y - g1.y));
    o1.z = gelu_f(b1.z + cb * (s1.z - g1.z));
    o1.w = gelu_f(b1.w + cb * (s1.w - g1.w));
    float4* orowb = (float4*)(out + (row0 + 1) * D);
    orowb[tid] = o0; orowb[tid + 256] = o1;
}

extern "C" void kernel_launch(void* const* d_in, const int* in_sizes, int n_in,
                              void* d_out, int out_size, void* d_ws, size_t ws_size,
                              hipStream_t stream) {
    const float* x          = (const float*)d_in[0];
    const float* log_inject = (const float*)d_in[1];
    const float* buf        = (const float*)d_in[2];
    const float* xbuf       = (const float*)d_in[3];
    const float* inj        = (const float*)d_in[4];
    const float* xglobal    = (const float*)d_in[5];
    const int*   mask       = (const int*)d_in[6];
    float* out = (float*)d_out;
    float* ws  = (float*)d_ws;

    float* ysum    = ws;                                // [2048]
    float* dotv    = ws + 2048;                         // [512]
    float* bn2     = ws + 2560;                         // [512]
    float* yn2     = ws + 3072;                         // [1]
    float* scal    = ws + 3076;                         // [4]
    unsigned int* counter = (unsigned int*)(ws + 3080); // [1]
    float* partial = ws + 4096;                         // [RC * D] = 2 MB

    k1_colsum<<<dim3(2, RC), 256, 0, stream>>>(x, partial);
    k1b_reduce<<<64, 256, 0, stream>>>(partial, ysum, counter);
    k2_sims_select<<<NBUF + 1, 256, 0, stream>>>(buf, ysum, dotv, bn2, yn2,
                                                 mask, inj, log_inject,
                                                 xbuf, xglobal, scal, counter);
    k4_out<<<NROWS / K4_ROWS, 256, 0, stream>>>(x, xbuf, xglobal, scal, out);
}

// Round 4
// 57.570 us; speedup vs baseline: 8.0555x; 1.0790x over previous
//
#include <hip/hip_runtime.h>
#include <math.h>

#define D 2048
#define NROWS 8192      // B*T = 4*2048
#define NBUF 512
#define RC 128          // row chunks in k1 (partial = RC*D*4 = 1 MB in ws)
#define ROWS_PER_CHUNK 64

// tanh-GELU via sigmoid identity: 0.5*x*(1+tanh(a*(x+0.044715 x^3))) = x*sigmoid(2*a*u)
__device__ __forceinline__ float gelu_f(float v) {
    float u = v * (1.0f + 0.044715f * v * v);
    float t = -2.0f * 0.7978845608028654f * u;
    return v / (1.0f + __expf(t));
}

// ---- k1: partial column sums of gelu(x). grid (2, RC), block 256.  (exact R0 config)
__global__ __launch_bounds__(256) void k1_colsum(const float* __restrict__ x,
                                                 float* __restrict__ partial) {
    const int cg = blockIdx.x * 256 + threadIdx.x;   // float4 column group [0,512)
    const int r0 = blockIdx.y * ROWS_PER_CHUNK;
    const float4* x4 = (const float4*)x;
    float ax = 0.f, ay = 0.f, az = 0.f, aw = 0.f;
    #pragma unroll 4
    for (int r = 0; r < ROWS_PER_CHUNK; ++r) {
        float4 v = x4[(size_t)(r0 + r) * (D / 4) + cg];
        ax += gelu_f(v.x); ay += gelu_f(v.y); az += gelu_f(v.z); aw += gelu_f(v.w);
    }
    float4 o; o.x = ax; o.y = ay; o.z = az; o.w = aw;
    ((float4*)partial)[(size_t)blockIdx.y * (D / 4) + cg] = o;
}

// ---- k1b: reduce RC partials -> ysum[D]. grid 64, block 256 (32 cols x 8 k-slices).
__global__ __launch_bounds__(256) void k1b_reduce(const float* __restrict__ partial,
                                                  float* __restrict__ ysum) {
    const int tid = threadIdx.x;
    const int col   = blockIdx.x * 32 + (tid & 31);
    const int slice = tid >> 5;                        // 8 slices of RC/8 k-values
    const int k0 = slice * (RC / 8);
    float s = 0.f;
    #pragma unroll 16
    for (int k = 0; k < RC / 8; ++k) s += partial[(size_t)(k0 + k) * D + col];
    __shared__ float red[256];
    red[tid] = s;
    __syncthreads();
    if (tid < 32) {
        float t = red[tid];
        #pragma unroll
        for (int j = 1; j < 8; ++j) t += red[j * 32 + tid];
        ysum[blockIdx.x * 32 + tid] = t;
    }
}

// ---- k2: per-buf-row dot and norm2; block NBUF computes ||y_sum||^2. grid NBUF+1.
__global__ __launch_bounds__(256) void k2_sims(const float* __restrict__ buf,
                                               const float* __restrict__ ysum,
                                               float* __restrict__ dotv,
                                               float* __restrict__ bn2,
                                               float* __restrict__ yn2) {
    const int tid = threadIdx.x;
    const int b = blockIdx.x;
    float dacc = 0.f, nacc = 0.f;
    const float4* y4 = (const float4*)ysum;
    if (b < NBUF) {
        const float4* b4 = (const float4*)(buf + (size_t)b * D);
        #pragma unroll
        for (int c = tid; c < D / 4; c += 256) {
            float4 bv = b4[c]; float4 yv = y4[c];
            dacc += bv.x * yv.x + bv.y * yv.y + bv.z * yv.z + bv.w * yv.w;
            nacc += bv.x * bv.x + bv.y * bv.y + bv.z * bv.z + bv.w * bv.w;
        }
    } else {
        #pragma unroll
        for (int c = tid; c < D / 4; c += 256) {
            float4 yv = y4[c];
            dacc += yv.x * yv.x + yv.y * yv.y + yv.z * yv.z + yv.w * yv.w;
        }
    }
    #pragma unroll
    for (int off = 32; off; off >>= 1) {
        dacc += __shfl_down(dacc, off, 64);
        nacc += __shfl_down(nacc, off, 64);
    }
    __shared__ float sa[4], sb[4];
    const int lane = tid & 63, w = tid >> 6;
    if (lane == 0) { sa[w] = dacc; sb[w] = nacc; }
    __syncthreads();
    if (tid == 0) {
        float dt = sa[0] + sa[1] + sa[2] + sa[3];
        float nt = sb[0] + sb[1] + sb[2] + sb[3];
        if (b < NBUF) { dotv[b] = dt; bn2[b] = nt; }
        else yn2[0] = dt;
    }
}

// ---- k4: per-row. Phase 0: every block redundantly recomputes the selection
//      (argmax over 512 sims + inj_level) — deterministic, no fence needed since
//      k2's outputs are visible at the kernel boundary. Phase 1: tok_sim + output.
__global__ __launch_bounds__(256) void k4_out(const float* __restrict__ x,
                                              const float* __restrict__ xbuf,
                                              const float* __restrict__ xglobal,
                                              const float* __restrict__ dotv,
                                              const float* __restrict__ bn2,
                                              const float* __restrict__ yn2,
                                              const int* __restrict__ mask,
                                              const float* __restrict__ inj,
                                              const float* __restrict__ log_inject,
                                              float* __restrict__ out) {
    const int tid = threadIdx.x;
    const int lane = tid & 63, w = tid >> 6;
    const size_t row = blockIdx.x;

    // ---------- phase 0: selection (all blocks identical) ----------
    __shared__ float sv[4]; __shared__ int si[4];
    __shared__ int s_idx; __shared__ float s_lvl;
    {
        const float nm = fmaxf(sqrtf(yn2[0]) * (1.0f / 8192.0f), 1e-12f);
        const float rnm = 1.0f / nm;
        // two candidates per thread: i = tid, tid+256
        float bv; int bi;
        {
            const int i = tid;
            float nb = fmaxf(sqrtf(bn2[i]), 1e-12f);
            float sim = (dotv[i] * (1.0f / 8192.0f)) * rnm / nb;
            if (!mask[i]) sim = -1.0f;
            bv = sim; bi = i;
        }
        {
            const int i = tid + 256;
            float nb = fmaxf(sqrtf(bn2[i]), 1e-12f);
            float sim = (dotv[i] * (1.0f / 8192.0f)) * rnm / nb;
            if (!mask[i]) sim = -1.0f;
            if (sim > bv) { bv = sim; bi = i; }           // tie keeps lower index
        }
        #pragma unroll
        for (int off = 32; off; off >>= 1) {
            float ov = __shfl_down(bv, off, 64);
            int   oi = __shfl_down(bi, off, 64);
            if (ov > bv || (ov == bv && oi < bi)) { bv = ov; bi = oi; }
        }
        if (lane == 0) { sv[w] = bv; si[w] = bi; }
        __syncthreads();
        if (tid == 0) {
            float fv = sv[0]; int fi = si[0];
            #pragma unroll
            for (int j = 1; j < 4; ++j) {
                if (sv[j] > fv || (sv[j] == fv && si[j] < fi)) { fv = sv[j]; fi = si[j]; }
            }
            float ib = fminf(fmaxf(__expf(log_inject[0]), 0.001f), 2.0f);
            float inear = inj[fi];
            s_lvl = (fv > 0.85f) ? ((inear < 1e-6f) ? ib : inear * 2.0f) : inear;
            s_idx = fi;
        }
        __syncthreads();
    }
    const int   idx       = s_idx;
    const float inj_level = s_lvl;

    // ---------- phase 1: row loads + 4-way reduction ----------
    const float4* xr = (const float4*)(x + row * D);
    const float4* sr = (const float4*)(xbuf + (size_t)idx * D);
    const float4* gr = (const float4*)xglobal;

    float4 x0 = xr[tid], x1 = xr[tid + 256];
    float4 s0 = sr[tid], s1 = sr[tid + 256];
    float4 g0 = gr[tid], g1 = gr[tid + 256];

    float dxs = x0.x * s0.x + x0.y * s0.y + x0.z * s0.z + x0.w * s0.w
              + x1.x * s1.x + x1.y * s1.y + x1.z * s1.z + x1.w * s1.w;
    float dxx = x0.x * x0.x + x0.y * x0.y + x0.z * x0.z + x0.w * x0.w
              + x1.x * x1.x + x1.y * x1.y + x1.z * x1.z + x1.w * x1.w;
    float n2, s2;
    {
        float n0x = s0.x - g0.x, n0y = s0.y - g0.y, n0z = s0.z - g0.z, n0w = s0.w - g0.w;
        float n1x = s1.x - g1.x, n1y = s1.y - g1.y, n1z = s1.z - g1.z, n1w = s1.w - g1.w;
        n2 = n0x * n0x + n0y * n0y + n0z * n0z + n0w * n0w
           + n1x * n1x + n1y * n1y + n1z * n1z + n1w * n1w;
        s2 = s0.x * s0.x + s0.y * s0.y + s0.z * s0.z + s0.w * s0.w
           + s1.x * s1.x + s1.y * s1.y + s1.z * s1.z + s1.w * s1.w;
    }

    #pragma unroll
    for (int off = 32; off; off >>= 1) {
        dxs += __shfl_down(dxs, off, 64);
        dxx += __shfl_down(dxx, off, 64);
        n2  += __shfl_down(n2,  off, 64);
        s2  += __shfl_down(s2,  off, 64);
    }
    __shared__ float sa[4], sb[4], sc[4], sd[4];
    if (lane == 0) { sa[w] = dxs; sb[w] = dxx; sc[w] = n2; sd[w] = s2; }
    __syncthreads();
    __shared__ float s_coef;
    if (tid == 0) {
        float dt = sa[0] + sa[1] + sa[2] + sa[3];
        float nt = sb[0] + sb[1] + sb[2] + sb[3];
        float nn = sc[0] + sc[1] + sc[2] + sc[3];
        float ss = sd[0] + sd[1] + sd[2] + sd[3];
        float rnudge  = 1.0f / fmaxf(sqrtf(nn), 1e-6f);
        float rstored = 1.0f / fmaxf(sqrtf(ss), 1e-12f);
        float rx = 1.0f / fmaxf(sqrtf(nt), 1e-12f);
        float ts = fminf(fmaxf(dt * rx * rstored, 0.0f), 1.0f);  // tok_sim
        s_coef = (inj_level < 1e-6f) ? 0.0f : inj_level * ts * rnudge;
    }
    __syncthreads();
    const float c = s_coef;

    float4 o0, o1;
    o0.x = gelu_f(x0.x + c * (s0.x - g0.x));
    o0.y = gelu_f(x0.y + c * (s0.y - g0.y));
    o0.z = gelu_f(x0.z + c * (s0.z - g0.z));
    o0.w = gelu_f(x0.w + c * (s0.w - g0.w));
    o1.x = gelu_f(x1.x + c * (s1.x - g1.x));
    o1.y = gelu_f(x1.y + c * (s1.y - g1.y));
    o1.z = gelu_f(x1.z + c * (s1.z - g1.z));
    o1.w = gelu_f(x1.w + c * (s1.w - g1.w));

    float4* orow = (float4*)(out + row * D);
    orow[tid] = o0; orow[tid + 256] = o1;
}

extern "C" void kernel_launch(void* const* d_in, const int* in_sizes, int n_in,
                              void* d_out, int out_size, void* d_ws, size_t ws_size,
                              hipStream_t stream) {
    const float* x          = (const float*)d_in[0];
    const float* log_inject = (const float*)d_in[1];
    const float* buf        = (const float*)d_in[2];
    const float* xbuf       = (const float*)d_in[3];
    const float* inj        = (const float*)d_in[4];
    const float* xglobal    = (const float*)d_in[5];
    const int*   mask       = (const int*)d_in[6];
    float* out = (float*)d_out;
    float* ws  = (float*)d_ws;

    float* ysum    = ws;            // [2048]
    float* dotv    = ws + 2048;     // [512]
    float* bn2     = ws + 2560;     // [512]
    float* yn2     = ws + 3072;     // [1]
    float* partial = ws + 4096;     // [RC * D] = 1 MB

    k1_colsum<<<dim3(2, RC), 256, 0, stream>>>(x, partial);
    k1b_reduce<<<64, 256, 0, stream>>>(partial, ysum);
    k2_sims<<<NBUF + 1, 256, 0, stream>>>(buf, ysum, dotv, bn2, yn2);
    k4_out<<<NROWS, 256, 0, stream>>>(x, xbuf, xglobal, dotv, bn2, yn2,
                                      mask, inj, log_inject, out);
}

// Round 5
// 46.704 us; speedup vs baseline: 9.9297x; 1.2327x over previous
//
#include <hip/hip_runtime.h>
#include <math.h>

#define D 2048
#define NROWS 8192      // B*T = 4*2048
#define NBUF 512
#define RC 128          // row chunks in k1 (partial = RC*D*4 = 1 MB in ws)
#define ROWS_PER_CHUNK 64
#define K4_ROWS 2       // rows per k4 block

__device__ __forceinline__ float rcpf(float v) { return __builtin_amdgcn_rcpf(v); }

// tanh-GELU via sigmoid identity, division-free: x*sigmoid(2*a*(x+0.044715x^3))
__device__ __forceinline__ float gelu_f(float v) {
    float u = v * (1.0f + 0.044715f * v * v);
    float t = -1.5957691216057308f * u;            // -2*sqrt(2/pi)*u
    return v * rcpf(1.0f + __expf(t));
}

// ---- k1: partial column sums of gelu(x). grid (2, RC), block 256.
__global__ __launch_bounds__(256) void k1_colsum(const float* __restrict__ x,
                                                 float* __restrict__ partial) {
    const int cg = blockIdx.x * 256 + threadIdx.x;   // float4 column group [0,512)
    const int r0 = blockIdx.y * ROWS_PER_CHUNK;
    const float4* x4 = (const float4*)x;
    float ax = 0.f, ay = 0.f, az = 0.f, aw = 0.f;
    #pragma unroll 4
    for (int r = 0; r < ROWS_PER_CHUNK; ++r) {
        float4 v = x4[(size_t)(r0 + r) * (D / 4) + cg];
        ax += gelu_f(v.x); ay += gelu_f(v.y); az += gelu_f(v.z); aw += gelu_f(v.w);
    }
    float4 o; o.x = ax; o.y = ay; o.z = az; o.w = aw;
    ((float4*)partial)[(size_t)blockIdx.y * (D / 4) + cg] = o;
}

// ---- k1b: reduce RC partials -> ysum[D]. grid 64, block 256 (32 cols x 8 k-slices).
__global__ __launch_bounds__(256) void k1b_reduce(const float* __restrict__ partial,
                                                  float* __restrict__ ysum) {
    const int tid = threadIdx.x;
    const int col   = blockIdx.x * 32 + (tid & 31);
    const int slice = tid >> 5;
    const int k0 = slice * (RC / 8);
    float s = 0.f;
    #pragma unroll 16
    for (int k = 0; k < RC / 8; ++k) s += partial[(size_t)(k0 + k) * D + col];
    __shared__ float red[256];
    red[tid] = s;
    __syncthreads();
    if (tid < 32) {
        float t = red[tid];
        #pragma unroll
        for (int j = 1; j < 8; ++j) t += red[j * 32 + tid];
        ysum[blockIdx.x * 32 + tid] = t;
    }
}

// ---- k2: per-buf-row dot + ||buf_b||^2, plus ||xbuf_b||^2 and ||xbuf_b - xg||^2
//      (hoisted out of k4). Block NBUF computes ||ysum||^2. grid NBUF+1.
__global__ __launch_bounds__(256) void k2_sims(const float* __restrict__ buf,
                                               const float* __restrict__ xbuf,
                                               const float* __restrict__ xglobal,
                                               const float* __restrict__ ysum,
                                               float* __restrict__ dotv,
                                               float* __restrict__ bn2,
                                               float* __restrict__ xn2,
                                               float* __restrict__ nd2,
                                               float* __restrict__ yn2) {
    const int tid = threadIdx.x;
    const int b = blockIdx.x;
    float dacc = 0.f, nacc = 0.f, xacc = 0.f, ndacc = 0.f;
    const float4* y4 = (const float4*)ysum;
    if (b < NBUF) {
        const float4* b4 = (const float4*)(buf + (size_t)b * D);
        const float4* s4 = (const float4*)(xbuf + (size_t)b * D);
        const float4* g4 = (const float4*)xglobal;
        #pragma unroll
        for (int c = tid; c < D / 4; c += 256) {
            float4 bv = b4[c]; float4 yv = y4[c];
            float4 sv = s4[c]; float4 gv = g4[c];
            dacc += bv.x * yv.x + bv.y * yv.y + bv.z * yv.z + bv.w * yv.w;
            nacc += bv.x * bv.x + bv.y * bv.y + bv.z * bv.z + bv.w * bv.w;
            xacc += sv.x * sv.x + sv.y * sv.y + sv.z * sv.z + sv.w * sv.w;
            float nx = sv.x - gv.x, ny = sv.y - gv.y, nz = sv.z - gv.z, nw = sv.w - gv.w;
            ndacc += nx * nx + ny * ny + nz * nz + nw * nw;
        }
    } else {
        #pragma unroll
        for (int c = tid; c < D / 4; c += 256) {
            float4 yv = y4[c];
            dacc += yv.x * yv.x + yv.y * yv.y + yv.z * yv.z + yv.w * yv.w;
        }
    }
    #pragma unroll
    for (int off = 32; off; off >>= 1) {
        dacc  += __shfl_down(dacc,  off, 64);
        nacc  += __shfl_down(nacc,  off, 64);
        xacc  += __shfl_down(xacc,  off, 64);
        ndacc += __shfl_down(ndacc, off, 64);
    }
    __shared__ float sa[4], sb[4], sc[4], sd[4];
    const int lane = tid & 63, w = tid >> 6;
    if (lane == 0) { sa[w] = dacc; sb[w] = nacc; sc[w] = xacc; sd[w] = ndacc; }
    __syncthreads();
    if (tid == 0) {
        float dt = sa[0] + sa[1] + sa[2] + sa[3];
        float nt = sb[0] + sb[1] + sb[2] + sb[3];
        float xt = sc[0] + sc[1] + sc[2] + sc[3];
        float nd = sd[0] + sd[1] + sd[2] + sd[3];
        if (b < NBUF) { dotv[b] = dt; bn2[b] = nt; xn2[b] = xt; nd2[b] = nd; }
        else yn2[0] = dt;
    }
}

// ---- k4: 2 rows/block. Phase 0: redundant per-block selection (deterministic,
//      no fence — k2 outputs visible at kernel boundary). Phase 1: tok_sims + out.
__global__ __launch_bounds__(256) void k4_out(const float* __restrict__ x,
                                              const float* __restrict__ xbuf,
                                              const float* __restrict__ xglobal,
                                              const float* __restrict__ dotv,
                                              const float* __restrict__ bn2,
                                              const float* __restrict__ xn2,
                                              const float* __restrict__ nd2,
                                              const float* __restrict__ yn2,
                                              const int* __restrict__ mask,
                                              const float* __restrict__ inj,
                                              const float* __restrict__ log_inject,
                                              float* __restrict__ out) {
    const int tid = threadIdx.x;
    const int lane = tid & 63, w = tid >> 6;
    const size_t row0 = (size_t)blockIdx.x * K4_ROWS;

    // ---------- phase 0: selection (identical in every block) ----------
    __shared__ float sv[4]; __shared__ int si[4];
    __shared__ int s_idx;
    __shared__ float s_lvl, s_rnudge, s_rstored;
    {
        const float rnm = rcpf(fmaxf(sqrtf(yn2[0]) * (1.0f / 8192.0f), 1e-12f));
        float bv; int bi;
        {
            const int i = tid;
            float nb = fmaxf(sqrtf(bn2[i]), 1e-12f);
            float sim = (dotv[i] * (1.0f / 8192.0f)) * rnm * rcpf(nb);
            if (!mask[i]) sim = -1.0f;
            bv = sim; bi = i;
        }
        {
            const int i = tid + 256;
            float nb = fmaxf(sqrtf(bn2[i]), 1e-12f);
            float sim = (dotv[i] * (1.0f / 8192.0f)) * rnm * rcpf(nb);
            if (!mask[i]) sim = -1.0f;
            if (sim > bv) { bv = sim; bi = i; }           // tie keeps lower index
        }
        #pragma unroll
        for (int off = 32; off; off >>= 1) {
            float ov = __shfl_down(bv, off, 64);
            int   oi = __shfl_down(bi, off, 64);
            if (ov > bv || (ov == bv && oi < bi)) { bv = ov; bi = oi; }
        }
        if (lane == 0) { sv[w] = bv; si[w] = bi; }
        __syncthreads();
        if (tid == 0) {
            float fv = sv[0]; int fi = si[0];
            #pragma unroll
            for (int j = 1; j < 4; ++j) {
                if (sv[j] > fv || (sv[j] == fv && si[j] < fi)) { fv = sv[j]; fi = si[j]; }
            }
            float ib = fminf(fmaxf(__expf(log_inject[0]), 0.001f), 2.0f);
            float inear = inj[fi];
            s_lvl = (fv > 0.85f) ? ((inear < 1e-6f) ? ib : inear * 2.0f) : inear;
            s_idx = fi;
            s_rnudge  = rcpf(fmaxf(sqrtf(nd2[fi]), 1e-6f));
            s_rstored = rcpf(fmaxf(sqrtf(xn2[fi]), 1e-12f));
        }
        __syncthreads();
    }
    const int   idx       = s_idx;
    const float inj_level = s_lvl;
    const float rnudge    = s_rnudge;
    const float rstored   = s_rstored;

    // ---------- phase 1: two rows ----------
    const float4* sr = (const float4*)(xbuf + (size_t)idx * D);
    const float4* gr = (const float4*)xglobal;
    const float4 s0 = sr[tid], s1 = sr[tid + 256];
    const float4 g0 = gr[tid], g1 = gr[tid + 256];

    const float4* xra = (const float4*)(x + row0 * D);
    const float4* xrb = (const float4*)(x + (row0 + 1) * D);
    const float4 a0 = xra[tid], a1 = xra[tid + 256];
    const float4 b0 = xrb[tid], b1 = xrb[tid + 256];

    float das = a0.x * s0.x + a0.y * s0.y + a0.z * s0.z + a0.w * s0.w
              + a1.x * s1.x + a1.y * s1.y + a1.z * s1.z + a1.w * s1.w;
    float dax = a0.x * a0.x + a0.y * a0.y + a0.z * a0.z + a0.w * a0.w
              + a1.x * a1.x + a1.y * a1.y + a1.z * a1.z + a1.w * a1.w;
    float dbs = b0.x * s0.x + b0.y * s0.y + b0.z * s0.z + b0.w * s0.w
              + b1.x * s1.x + b1.y * s1.y + b1.z * s1.z + b1.w * s1.w;
    float dbx = b0.x * b0.x + b0.y * b0.y + b0.z * b0.z + b0.w * b0.w
              + b1.x * b1.x + b1.y * b1.y + b1.z * b1.z + b1.w * b1.w;

    #pragma unroll
    for (int off = 32; off; off >>= 1) {
        das += __shfl_down(das, off, 64);
        dax += __shfl_down(dax, off, 64);
        dbs += __shfl_down(dbs, off, 64);
        dbx += __shfl_down(dbx, off, 64);
    }
    __shared__ float sas[4], sax[4], sbs[4], sbx[4];
    if (lane == 0) { sas[w] = das; sax[w] = dax; sbs[w] = dbs; sbx[w] = dbx; }
    __syncthreads();
    __shared__ float s_ca, s_cb;
    if (tid == 0) {
        float dta = sas[0] + sas[1] + sas[2] + sas[3];
        float nta = sax[0] + sax[1] + sax[2] + sax[3];
        float rxa = rcpf(fmaxf(sqrtf(nta), 1e-12f));
        float tsa = fminf(fmaxf(dta * rxa * rstored, 0.0f), 1.0f);
        s_ca = (inj_level < 1e-6f) ? 0.0f : inj_level * tsa * rnudge;
        float dtb = sbs[0] + sbs[1] + sbs[2] + sbs[3];
        float ntb = sbx[0] + sbx[1] + sbx[2] + sbx[3];
        float rxb = rcpf(fmaxf(sqrtf(ntb), 1e-12f));
        float tsb = fminf(fmaxf(dtb * rxb * rstored, 0.0f), 1.0f);
        s_cb = (inj_level < 1e-6f) ? 0.0f : inj_level * tsb * rnudge;
    }
    __syncthreads();
    const float ca = s_ca, cb = s_cb;

    float4 o0, o1;
    o0.x = gelu_f(a0.x + ca * (s0.x - g0.x));
    o0.y = gelu_f(a0.y + ca * (s0.y - g0.y));
    o0.z = gelu_f(a0.z + ca * (s0.z - g0.z));
    o0.w = gelu_f(a0.w + ca * (s0.w - g0.w));
    o1.x = gelu_f(a1.x + ca * (s1.x - g1.x));
    o1.y = gelu_f(a1.y + ca * (s1.y - g1.y));
    o1.z = gelu_f(a1.z + ca * (s1.z - g1.z));
    o1.w = gelu_f(a1.w + ca * (s1.w - g1.w));
    float4* orowa = (float4*)(out + row0 * D);
    orowa[tid] = o0; orowa[tid + 256] = o1;

    o0.x = gelu_f(b0.x + cb * (s0.x - g0.x));
    o0.y = gelu_f(b0.y + cb * (s0.y - g0.y));
    o0.z = gelu_f(b0.z + cb * (s0.z - g0.z));
    o0.w = gelu_f(b0.w + cb * (s0.w - g0.w));
    o1.x = gelu_f(b1.x + cb * (s1.x - g1.x));
    o1.y = gelu_f(b1.y + cb * (s1.y - g1.y));
    o1.z = gelu_f(b1.z + cb * (s1.z - g1.z));
    o1.w = gelu_f(b1.w + cb * (s1.w - g1.w));
    float4* orowb = (float4*)(out + (row0 + 1) * D);
    orowb[tid] = o0; orowb[tid + 256] = o1;
}

extern "C" void kernel_launch(void* const* d_in, const int* in_sizes, int n_in,
                              void* d_out, int out_size, void* d_ws, size_t ws_size,
                              hipStream_t stream) {
    const float* x          = (const float*)d_in[0];
    const float* log_inject = (const float*)d_in[1];
    const float* buf        = (const float*)d_in[2];
    const float* xbuf       = (const float*)d_in[3];
    const float* inj        = (const float*)d_in[4];
    const float* xglobal    = (const float*)d_in[5];
    const int*   mask       = (const int*)d_in[6];
    float* out = (float*)d_out;
    float* ws  = (float*)d_ws;

    float* ysum    = ws;            // [2048]
    float* dotv    = ws + 2048;     // [512]
    float* bn2     = ws + 2560;     // [512]
    float* xn2     = ws + 3072;     // [512]
    float* nd2     = ws + 3584;     // [512]
    float* yn2     = ws + 4088;     // [1]
    float* partial = ws + 4096;     // [RC * D] = 1 MB

    k1_colsum<<<dim3(2, RC), 256, 0, stream>>>(x, partial);
    k1b_reduce<<<64, 256, 0, stream>>>(partial, ysum);
    k2_sims<<<NBUF + 1, 256, 0, stream>>>(buf, xbuf, xglobal, ysum,
                                          dotv, bn2, xn2, nd2, yn2);
    k4_out<<<NROWS / K4_ROWS, 256, 0, stream>>>(x, xbuf, xglobal, dotv, bn2,
                                                xn2, nd2, yn2, mask, inj,
                                                log_inject, out);
}

// Round 6
// 44.046 us; speedup vs baseline: 10.5289x; 1.0603x over previous
//
#include <hip/hip_runtime.h>
#include <math.h>

#define D 2048
#define NROWS 8192      // B*T = 4*2048
#define NBUF 512
#define RC 128          // row chunks in k1 (partial = RC*D*4 = 1 MB in ws)
#define ROWS_PER_CHUNK 64
#define K4_ROWS 4       // rows per k4 block

__device__ __forceinline__ float rcpf(float v) { return __builtin_amdgcn_rcpf(v); }

// tanh-GELU via sigmoid identity, division-free: x*sigmoid(2*a*(x+0.044715x^3))
__device__ __forceinline__ float gelu_f(float v) {
    float u = v * (1.0f + 0.044715f * v * v);
    float t = -1.5957691216057308f * u;            // -2*sqrt(2/pi)*u
    return v * rcpf(1.0f + __expf(t));
}

__device__ __forceinline__ float dot8(float4 p0, float4 p1, float4 q0, float4 q1) {
    return p0.x * q0.x + p0.y * q0.y + p0.z * q0.z + p0.w * q0.w
         + p1.x * q1.x + p1.y * q1.y + p1.z * q1.z + p1.w * q1.w;
}

// ---- k1: partial column sums of gelu(x). grid (2, RC), block 256.
__global__ __launch_bounds__(256) void k1_colsum(const float* __restrict__ x,
                                                 float* __restrict__ partial) {
    const int cg = blockIdx.x * 256 + threadIdx.x;   // float4 column group [0,512)
    const int r0 = blockIdx.y * ROWS_PER_CHUNK;
    const float4* x4 = (const float4*)x;
    float ax = 0.f, ay = 0.f, az = 0.f, aw = 0.f;
    #pragma unroll 4
    for (int r = 0; r < ROWS_PER_CHUNK; ++r) {
        float4 v = x4[(size_t)(r0 + r) * (D / 4) + cg];
        ax += gelu_f(v.x); ay += gelu_f(v.y); az += gelu_f(v.z); aw += gelu_f(v.w);
    }
    float4 o; o.x = ax; o.y = ay; o.z = az; o.w = aw;
    ((float4*)partial)[(size_t)blockIdx.y * (D / 4) + cg] = o;
}

// ---- k1b: reduce RC partials -> ysum[D]. grid 64, block 256 (32 cols x 8 k-slices).
__global__ __launch_bounds__(256) void k1b_reduce(const float* __restrict__ partial,
                                                  float* __restrict__ ysum) {
    const int tid = threadIdx.x;
    const int col   = blockIdx.x * 32 + (tid & 31);
    const int slice = tid >> 5;
    const int k0 = slice * (RC / 8);
    float s = 0.f;
    #pragma unroll 16
    for (int k = 0; k < RC / 8; ++k) s += partial[(size_t)(k0 + k) * D + col];
    __shared__ float red[256];
    red[tid] = s;
    __syncthreads();
    if (tid < 32) {
        float t = red[tid];
        #pragma unroll
        for (int j = 1; j < 8; ++j) t += red[j * 32 + tid];
        ysum[blockIdx.x * 32 + tid] = t;
    }
}

// ---- k2: per-buf-row dot + ||buf_b||^2, plus ||xbuf_b||^2 and ||xbuf_b - xg||^2
//      (hoisted out of k4). Block NBUF computes ||ysum||^2. grid NBUF+1.
__global__ __launch_bounds__(256) void k2_sims(const float* __restrict__ buf,
                                               const float* __restrict__ xbuf,
                                               const float* __restrict__ xglobal,
                                               const float* __restrict__ ysum,
                                               float* __restrict__ dotv,
                                               float* __restrict__ bn2,
                                               float* __restrict__ xn2,
                                               float* __restrict__ nd2,
                                               float* __restrict__ yn2) {
    const int tid = threadIdx.x;
    const int b = blockIdx.x;
    float dacc = 0.f, nacc = 0.f, xacc = 0.f, ndacc = 0.f;
    const float4* y4 = (const float4*)ysum;
    if (b < NBUF) {
        const float4* b4 = (const float4*)(buf + (size_t)b * D);
        const float4* s4 = (const float4*)(xbuf + (size_t)b * D);
        const float4* g4 = (const float4*)xglobal;
        #pragma unroll
        for (int c = tid; c < D / 4; c += 256) {
            float4 bv = b4[c]; float4 yv = y4[c];
            float4 sv = s4[c]; float4 gv = g4[c];
            dacc += bv.x * yv.x + bv.y * yv.y + bv.z * yv.z + bv.w * yv.w;
            nacc += bv.x * bv.x + bv.y * bv.y + bv.z * bv.z + bv.w * bv.w;
            xacc += sv.x * sv.x + sv.y * sv.y + sv.z * sv.z + sv.w * sv.w;
            float nx = sv.x - gv.x, ny = sv.y - gv.y, nz = sv.z - gv.z, nw = sv.w - gv.w;
            ndacc += nx * nx + ny * ny + nz * nz + nw * nw;
        }
    } else {
        #pragma unroll
        for (int c = tid; c < D / 4; c += 256) {
            float4 yv = y4[c];
            dacc += yv.x * yv.x + yv.y * yv.y + yv.z * yv.z + yv.w * yv.w;
        }
    }
    #pragma unroll
    for (int off = 32; off; off >>= 1) {
        dacc  += __shfl_down(dacc,  off, 64);
        nacc  += __shfl_down(nacc,  off, 64);
        xacc  += __shfl_down(xacc,  off, 64);
        ndacc += __shfl_down(ndacc, off, 64);
    }
    __shared__ float sa[4], sb[4], sc[4], sd[4];
    const int lane = tid & 63, w = tid >> 6;
    if (lane == 0) { sa[w] = dacc; sb[w] = nacc; sc[w] = xacc; sd[w] = ndacc; }
    __syncthreads();
    if (tid == 0) {
        float dt = sa[0] + sa[1] + sa[2] + sa[3];
        float nt = sb[0] + sb[1] + sb[2] + sb[3];
        float xt = sc[0] + sc[1] + sc[2] + sc[3];
        float nd = sd[0] + sd[1] + sd[2] + sd[3];
        if (b < NBUF) { dotv[b] = dt; bn2[b] = nt; xn2[b] = xt; nd2[b] = nd; }
        else yn2[0] = dt;
    }
}

// ---- k4: 4 rows/block. x loads issued FIRST (latency hides under phase 0).
//      Phase 0: redundant per-block selection (deterministic, no fence needed —
//      k2's outputs visible at kernel boundary). Phase 1: tok_sims + outputs.
__global__ __launch_bounds__(256) void k4_out(const float* __restrict__ x,
                                              const float* __restrict__ xbuf,
                                              const float* __restrict__ xglobal,
                                              const float* __restrict__ dotv,
                                              const float* __restrict__ bn2,
                                              const float* __restrict__ xn2,
                                              const float* __restrict__ nd2,
                                              const float* __restrict__ yn2,
                                              const int* __restrict__ mask,
                                              const float* __restrict__ inj,
                                              const float* __restrict__ log_inject,
                                              float* __restrict__ out) {
    const int tid = threadIdx.x;
    const int lane = tid & 63, w = tid >> 6;
    const size_t row0 = (size_t)blockIdx.x * K4_ROWS;

    // ---------- issue x loads early: 4 rows x 2 float4/thread ----------
    const float4* xr0 = (const float4*)(x + (row0 + 0) * D);
    const float4* xr1 = (const float4*)(x + (row0 + 1) * D);
    const float4* xr2 = (const float4*)(x + (row0 + 2) * D);
    const float4* xr3 = (const float4*)(x + (row0 + 3) * D);
    const float4 a0 = xr0[tid], a1 = xr0[tid + 256];
    const float4 b0 = xr1[tid], b1 = xr1[tid + 256];
    const float4 c0 = xr2[tid], c1 = xr2[tid + 256];
    const float4 d0 = xr3[tid], d1 = xr3[tid + 256];

    // ---------- phase 0: selection (identical in every block) ----------
    __shared__ float sv[4]; __shared__ int si[4];
    __shared__ int s_idx;
    __shared__ float s_lvl, s_rnudge, s_rstored;
    {
        const float rnm = rcpf(fmaxf(sqrtf(yn2[0]) * (1.0f / 8192.0f), 1e-12f));
        float bv; int bi;
        {
            const int i = tid;
            float nb = fmaxf(sqrtf(bn2[i]), 1e-12f);
            float sim = (dotv[i] * (1.0f / 8192.0f)) * rnm * rcpf(nb);
            if (!mask[i]) sim = -1.0f;
            bv = sim; bi = i;
        }
        {
            const int i = tid + 256;
            float nb = fmaxf(sqrtf(bn2[i]), 1e-12f);
            float sim = (dotv[i] * (1.0f / 8192.0f)) * rnm * rcpf(nb);
            if (!mask[i]) sim = -1.0f;
            if (sim > bv) { bv = sim; bi = i; }           // tie keeps lower index
        }
        #pragma unroll
        for (int off = 32; off; off >>= 1) {
            float ov = __shfl_down(bv, off, 64);
            int   oi = __shfl_down(bi, off, 64);
            if (ov > bv || (ov == bv && oi < bi)) { bv = ov; bi = oi; }
        }
        if (lane == 0) { sv[w] = bv; si[w] = bi; }
        __syncthreads();
        if (tid == 0) {
            float fv = sv[0]; int fi = si[0];
            #pragma unroll
            for (int j = 1; j < 4; ++j) {
                if (sv[j] > fv || (sv[j] == fv && si[j] < fi)) { fv = sv[j]; fi = si[j]; }
            }
            float ib = fminf(fmaxf(__expf(log_inject[0]), 0.001f), 2.0f);
            float inear = inj[fi];
            s_lvl = (fv > 0.85f) ? ((inear < 1e-6f) ? ib : inear * 2.0f) : inear;
            s_idx = fi;
            s_rnudge  = rcpf(fmaxf(sqrtf(nd2[fi]), 1e-6f));
            s_rstored = rcpf(fmaxf(sqrtf(xn2[fi]), 1e-12f));
        }
        __syncthreads();
    }
    const int   idx       = s_idx;
    const float inj_level = s_lvl;
    const float rnudge    = s_rnudge;
    const float rstored   = s_rstored;

    // ---------- phase 1: stored/global rows (reused by all 4 rows) ----------
    const float4* sr = (const float4*)(xbuf + (size_t)idx * D);
    const float4* gr = (const float4*)xglobal;
    const float4 s0 = sr[tid], s1 = sr[tid + 256];
    const float4 g0 = gr[tid], g1 = gr[tid + 256];

    float d0s = dot8(a0, a1, s0, s1), d0x = dot8(a0, a1, a0, a1);
    float d1s = dot8(b0, b1, s0, s1), d1x = dot8(b0, b1, b0, b1);
    float d2s = dot8(c0, c1, s0, s1), d2x = dot8(c0, c1, c0, c1);
    float d3s = dot8(d0, d1, s0, s1), d3x = dot8(d0, d1, d0, d1);

    #pragma unroll
    for (int off = 32; off; off >>= 1) {
        d0s += __shfl_down(d0s, off, 64);
        d0x += __shfl_down(d0x, off, 64);
        d1s += __shfl_down(d1s, off, 64);
        d1x += __shfl_down(d1x, off, 64);
        d2s += __shfl_down(d2s, off, 64);
        d2x += __shfl_down(d2x, off, 64);
        d3s += __shfl_down(d3s, off, 64);
        d3x += __shfl_down(d3x, off, 64);
    }
    __shared__ float red8[8][4];
    if (lane == 0) {
        red8[0][w] = d0s; red8[1][w] = d0x;
        red8[2][w] = d1s; red8[3][w] = d1x;
        red8[4][w] = d2s; red8[5][w] = d2x;
        red8[6][w] = d3s; red8[7][w] = d3x;
    }
    __syncthreads();
    __shared__ float s_c[4];
    if (tid < 4) {
        const int r = tid;
        float dt = red8[2 * r][0] + red8[2 * r][1] + red8[2 * r][2] + red8[2 * r][3];
        float nt = red8[2 * r + 1][0] + red8[2 * r + 1][1] + red8[2 * r + 1][2] + red8[2 * r + 1][3];
        float rx = rcpf(fmaxf(sqrtf(nt), 1e-12f));
        float ts = fminf(fmaxf(dt * rx * rstored, 0.0f), 1.0f);  // tok_sim
        s_c[r] = (inj_level < 1e-6f) ? 0.0f : inj_level * ts * rnudge;
    }
    __syncthreads();

    // diffs computed once, reused across 4 rows
    float4 f0, f1;
    f0.x = s0.x - g0.x; f0.y = s0.y - g0.y; f0.z = s0.z - g0.z; f0.w = s0.w - g0.w;
    f1.x = s1.x - g1.x; f1.y = s1.y - g1.y; f1.z = s1.z - g1.z; f1.w = s1.w - g1.w;

    {
        const float c = s_c[0];
        float4 o0, o1;
        o0.x = gelu_f(a0.x + c * f0.x); o0.y = gelu_f(a0.y + c * f0.y);
        o0.z = gelu_f(a0.z + c * f0.z); o0.w = gelu_f(a0.w + c * f0.w);
        o1.x = gelu_f(a1.x + c * f1.x); o1.y = gelu_f(a1.y + c * f1.y);
        o1.z = gelu_f(a1.z + c * f1.z); o1.w = gelu_f(a1.w + c * f1.w);
        float4* orow = (float4*)(out + (row0 + 0) * D);
        orow[tid] = o0; orow[tid + 256] = o1;
    }
    {
        const float c = s_c[1];
        float4 o0, o1;
        o0.x = gelu_f(b0.x + c * f0.x); o0.y = gelu_f(b0.y + c * f0.y);
        o0.z = gelu_f(b0.z + c * f0.z); o0.w = gelu_f(b0.w + c * f0.w);
        o1.x = gelu_f(b1.x + c * f1.x); o1.y = gelu_f(b1.y + c * f1.y);
        o1.z = gelu_f(b1.z + c * f1.z); o1.w = gelu_f(b1.w + c * f1.w);
        float4* orow = (float4*)(out + (row0 + 1) * D);
        orow[tid] = o0; orow[tid + 256] = o1;
    }
    {
        const float c = s_c[2];
        float4 o0, o1;
        o0.x = gelu_f(c0.x + c * f0.x); o0.y = gelu_f(c0.y + c * f0.y);
        o0.z = gelu_f(c0.z + c * f0.z); o0.w = gelu_f(c0.w + c * f0.w);
        o1.x = gelu_f(c1.x + c * f1.x); o1.y = gelu_f(c1.y + c * f1.y);
        o1.z = gelu_f(c1.z + c * f1.z); o1.w = gelu_f(c1.w + c * f1.w);
        float4* orow = (float4*)(out + (row0 + 2) * D);
        orow[tid] = o0; orow[tid + 256] = o1;
    }
    {
        const float c = s_c[3];
        float4 o0, o1;
        o0.x = gelu_f(d0.x + c * f0.x); o0.y = gelu_f(d0.y + c * f0.y);
        o0.z = gelu_f(d0.z + c * f0.z); o0.w = gelu_f(d0.w + c * f0.w);
        o1.x = gelu_f(d1.x + c * f1.x); o1.y = gelu_f(d1.y + c * f1.y);
        o1.z = gelu_f(d1.z + c * f1.z); o1.w = gelu_f(d1.w + c * f1.w);
        float4* orow = (float4*)(out + (row0 + 3) * D);
        orow[tid] = o0; orow[tid + 256] = o1;
    }
}

extern "C" void kernel_launch(void* const* d_in, const int* in_sizes, int n_in,
                              void* d_out, int out_size, void* d_ws, size_t ws_size,
                              hipStream_t stream) {
    const float* x          = (const float*)d_in[0];
    const float* log_inject = (const float*)d_in[1];
    const float* buf        = (const float*)d_in[2];
    const float* xbuf       = (const float*)d_in[3];
    const float* inj        = (const float*)d_in[4];
    const float* xglobal    = (const float*)d_in[5];
    const int*   mask       = (const int*)d_in[6];
    float* out = (float*)d_out;
    float* ws  = (float*)d_ws;

    float* ysum    = ws;            // [2048]
    float* dotv    = ws + 2048;     // [512]
    float* bn2     = ws + 2560;     // [512]
    float* xn2     = ws + 3072;     // [512]
    float* nd2     = ws + 3584;     // [512]
    float* yn2     = ws + 4088;     // [1]
    float* partial = ws + 4096;     // [RC * D] = 1 MB

    k1_colsum<<<dim3(2, RC), 256, 0, stream>>>(x, partial);
    k1b_reduce<<<64, 256, 0, stream>>>(partial, ysum);
    k2_sims<<<NBUF + 1, 256, 0, stream>>>(buf, xbuf, xglobal, ysum,
                                          dotv, bn2, xn2, nd2, yn2);
    k4_out<<<NROWS / K4_ROWS, 256, 0, stream>>>(x, xbuf, xglobal, dotv, bn2,
                                                xn2, nd2, yn2, mask, inj,
                                                log_inject, out);
}